// Round 7
// baseline (459.520 us; speedup 1.0000x reference)
//
#include <hip/hip_runtime.h>
#include <hip/hip_cooperative_groups.h>
#include <math.h>

namespace cg = cooperative_groups;

#define N_NODES 20000
#define N_EDGES 160000

#define NBINS   512                  // usable bins; bin 512 = endpoint r=7.5 (sv==0 there exactly)
#define BINS1   513                  // rows stored per pair
#define RMAX    7.5f

// ws layout (bytes). ~13.2 MB.
// ef rows are COMPACT: 16 floats = {sv[12], x, y, z, pad} = 64B, one cacheline/edge.
static const size_t OFF_EF  = 0;                                     // ef [E][16] f32 (node-grouped rows)
static const size_t OFF_T   = OFF_EF  + (size_t)N_EDGES * 16 * 4;    // T [100][64][12]
static const size_t OFF_G   = OFF_T   + (size_t)100 * 64 * 12 * 4;   // g_tT [64][513] (k-major)
static const size_t OFF_SV  = OFF_G   + (size_t)64 * BINS1 * 4;      // sv_table [100][513][12]
static const size_t OFF_NOFF= OFF_SV  + (size_t)100 * BINS1 * 12 * 4;// node_off [N+1] int
static const size_t OFF_NCNT= OFF_NOFF+ (size_t)(N_NODES + 1) * 4;   // cnt_i [N] int (zeroed)
static const size_t OFF_NCUR= OFF_NCNT+ (size_t)N_NODES * 4;         // node_cur [N] int (zeroed)

// phase-A task split: [0,25) ai+T build, [25,34) g-table, [34,659) histogram
#define P1_T_BLOCKS  25
#define P1_G_BLOCKS  9
#define P1_H_BLOCKS  625
#define P1_GRID (P1_T_BLOCKS + P1_G_BLOCKS + P1_H_BLOCKS)
// phase-B task split: [0,79) scan segments, [79,979) sv chunks (64 bins each)
#define P2_SCAN_BLOCKS 79
#define P2_CHUNKS 9
#define P2_GRID (P2_SCAN_BLOCKS + 100 * P2_CHUNKS)

#define FGRID 640                    // cooperative grid: 2.5 blocks/CU, safely co-resident

__device__ __forceinline__ float silu_f(float x) {
    return x / (1.0f + __expf(-x));
}

// ===================== phase bodies (shared by fused + fallback) =====================

__device__ __forceinline__ void phaseA_body(int bb, int tid, float* smem,
        const float* __restrict__ emb,
        const float* __restrict__ fw1, const float* __restrict__ fb1,
        const float* __restrict__ fw2, const float* __restrict__ fb2,
        const float* __restrict__ fw3, const float* __restrict__ fb3,
        const float* __restrict__ fc_w1, const float* __restrict__ fc_w2,
        const float* __restrict__ fc_w3, const float* __restrict__ fc_w4,
        const int* __restrict__ edst,
        float* __restrict__ T, float* __restrict__ g_tT,
        int* __restrict__ cnt_i) {
    if (bb < P1_T_BLOCKS) {
        // ---- inline node-type MLP (10 types) then T[pair][k][12] build ----
        float* h1s = smem;              // [10][64]
        float* h2s = smem + 640;        // [10][32]
        float* ai  = smem + 960;        // [10][8]
        for (int idx = tid; idx < 640; idx += 256) {
            int t = idx >> 6, j = idx & 63;
            float acc = fb1[j];
            #pragma unroll
            for (int i = 0; i < 16; i++) acc += emb[t * 16 + i] * fw1[i * 64 + j];
            h1s[idx] = silu_f(acc);
        }
        __syncthreads();
        for (int idx = tid; idx < 320; idx += 256) {
            int t = idx >> 5, j = idx & 31;
            float acc = fb2[j];
            #pragma unroll
            for (int i = 0; i < 64; i++) acc += h1s[t * 64 + i] * fw2[i * 32 + j];
            h2s[idx] = silu_f(acc);
        }
        __syncthreads();
        if (tid < 80) {
            int t = tid >> 3, j = tid & 7;
            float acc = fb3[j];
            #pragma unroll
            for (int i = 0; i < 32; i++) acc += h2s[t * 32 + i] * fw3[i * 8 + j];
            ai[tid] = acc;
        }
        __syncthreads();

        int idx = bb * 256 + tid;       // 6400 = 100 pairs x 64 k
        int pair = idx >> 6;
        int k = idx & 63;
        int ts = pair / 10, td = pair - ts * 10;
        float a[8], bbv[8];
        #pragma unroll
        for (int i = 0; i < 8; i++) a[i] = ai[ts * 8 + i];
        #pragma unroll
        for (int i = 0; i < 8; i++) bbv[i] = ai[td * 8 + i];
        float sv[12];
        #pragma unroll
        for (int i = 0; i < 12; i++) sv[i] = 0.0f;
        const float* wk = fc_w4 + k * 768;
        #pragma unroll 2
        for (int u = 0; u < 8; u++) {
            #pragma unroll
            for (int v = 0; v < 8; v++) {
                float ab = a[u] * bbv[v];
                const float* wp = wk + u * 32 + v * 4;
                float4 w0 = *(const float4*)(wp);
                float4 w1 = *(const float4*)(wp + 256);
                float4 w2 = *(const float4*)(wp + 512);
                sv[0] += ab * w0.x; sv[1] += ab * w0.y; sv[2]  += ab * w0.z; sv[3]  += ab * w0.w;
                sv[4] += ab * w1.x; sv[5] += ab * w1.y; sv[6]  += ab * w1.z; sv[7]  += ab * w1.w;
                sv[8] += ab * w2.x; sv[9] += ab * w2.y; sv[10] += ab * w2.z; sv[11] += ab * w2.w;
            }
        }
        float* tp = T + pair * 768 + k * 12;
        #pragma unroll
        for (int j = 0; j < 12; j++) tp[j] = sv[j];
        __syncthreads();                // smem reuse barrier (block may take another task)
    } else if (bb < P1_T_BLOCKS + P1_G_BLOCKS) {
        // ---- g-table, cooperative: 64 bins/block (lane=bin), wave owns 16 channels ----
        int lane = tid & 63;
        int wq = __builtin_amdgcn_readfirstlane(tid >> 6);
        int bin = (bb - P1_T_BLOCKS) * 64 + lane;
        bool valid = (bin <= NBINS);
        float r = (float)bin * (RMAX / (float)NBINS);

        float rb[16];
        const float step = 5.0f / 17.0f;
        const float istep = 17.0f / 5.0f;
        const float rsc = 4.0f / 1.12f;
        #pragma unroll
        for (int i = 0; i < 16; i++) {
            float dd = (r - (float)(i + 1) * step) * istep;
            rb[i] = __expf(-dd * dd) * rsc;
        }

        // L1: 16 -> 64 (weight addresses wave-uniform -> scalar loads)
        #pragma unroll
        for (int jj = 0; jj < 16; jj++) {
            int j = wq * 16 + jj;
            float a0 = 0, a1 = 0, a2 = 0, a3 = 0;
            #pragma unroll
            for (int i = 0; i < 16; i += 4) {
                a0 += rb[i]     * fc_w1[(i)     * 64 + j];
                a1 += rb[i + 1] * fc_w1[(i + 1) * 64 + j];
                a2 += rb[i + 2] * fc_w1[(i + 2) * 64 + j];
                a3 += rb[i + 3] * fc_w1[(i + 3) * 64 + j];
            }
            smem[j * 64 + lane] = silu_f(((a0 + a1) + (a2 + a3)) * 0.25f);
        }
        __syncthreads();

        // L2: 64 -> 64
        float acc[16];
        #pragma unroll
        for (int jj = 0; jj < 16; jj++) acc[jj] = 0.0f;
        #pragma unroll
        for (int c = 0; c < 4; c++) {
            float hc[16];
            #pragma unroll
            for (int i = 0; i < 16; i++) hc[i] = smem[(c * 16 + i) * 64 + lane];
            #pragma unroll
            for (int jj = 0; jj < 16; jj++) {
                int j = wq * 16 + jj;
                #pragma unroll
                for (int i = 0; i < 16; i++) acc[jj] += hc[i] * fc_w2[(c * 16 + i) * 64 + j];
            }
        }
        __syncthreads();
        #pragma unroll
        for (int jj = 0; jj < 16; jj++) smem[(wq * 16 + jj) * 64 + lane] = silu_f(acc[jj] * 0.125f);
        __syncthreads();

        // L3: 64 -> 64 -> g_tT[k][bin] (lane-coalesced stores)
        #pragma unroll
        for (int jj = 0; jj < 16; jj++) acc[jj] = 0.0f;
        #pragma unroll
        for (int c = 0; c < 4; c++) {
            float hc[16];
            #pragma unroll
            for (int i = 0; i < 16; i++) hc[i] = smem[(c * 16 + i) * 64 + lane];
            #pragma unroll
            for (int jj = 0; jj < 16; jj++) {
                int j = wq * 16 + jj;
                #pragma unroll
                for (int i = 0; i < 16; i++) acc[jj] += hc[i] * fc_w3[(c * 16 + i) * 64 + j];
            }
        }
        if (valid) {
            #pragma unroll
            for (int jj = 0; jj < 16; jj++)
                g_tT[(size_t)(wq * 16 + jj) * BINS1 + bin] = silu_f(acc[jj] * 0.125f);
        }
        __syncthreads();
    } else {
        // ---- histogram of edge_dst (20000 addresses: contention negligible) ----
        int e = (bb - P1_T_BLOCKS - P1_G_BLOCKS) * 256 + tid;
        if (e < N_EDGES) atomicAdd(&cnt_i[edst[e]], 1);
    }
}

__device__ __forceinline__ void phaseB_body(int bb, int tid, float* smem,
        const int* __restrict__ cnt_i, int* __restrict__ node_off,
        const float* __restrict__ T, const float* __restrict__ g_tT,
        float* __restrict__ sv_table) {
    if (bb < P2_SCAN_BLOCKS) {
        // Scan: independent 256-node segments; base = direct coalesced striped sum.
        int* wred = (int*)smem;         // [4] base partial reduce
        int* wsum = (int*)smem + 4;     // [4] per-wave scan totals
        int lane = tid & 63, w = tid >> 6;
        int nbase = bb * 256;
        int n = nbase + tid;
        int c = (n < N_NODES) ? cnt_i[n] : 0;        // coalesced

        int part = 0;
        for (int i = tid; i < nbase; i += 256) part += cnt_i[i];
        #pragma unroll
        for (int off = 1; off < 64; off <<= 1) part += __shfl_xor(part, off);
        if (lane == 0) wred[w] = part;

        int sc = c;
        #pragma unroll
        for (int off = 1; off < 64; off <<= 1) {
            int v2 = __shfl_up(sc, off);
            if (lane >= off) sc += v2;
        }
        if (lane == 63) wsum[w] = sc;
        __syncthreads();

        int base = wred[0] + wred[1] + wred[2] + wred[3];
        int wb = 0;
        #pragma unroll
        for (int i = 0; i < 4; i++) wb += (i < w) ? wsum[i] : 0;
        if (n < N_NODES) node_off[n] = base + wb + (sc - c);   // exclusive, coalesced
        if (bb == 0 && tid == 0) node_off[N_NODES] = N_EDGES;
        __syncthreads();
        return;
    }

    int idx = bb - P2_SCAN_BLOCKS;
    int pair = idx / P2_CHUNKS;
    int chunk = idx - pair * P2_CHUNKS;

    float* part = smem;                 // [4][64][13]
    float* Tlds = smem + 3328;          // [768]

    const float* Tp = T + pair * 768;
    #pragma unroll
    for (int i = tid; i < 768; i += 256) Tlds[i] = Tp[i];
    __syncthreads();

    int lane = tid & 63;                // bin within chunk
    int wq = tid >> 6;                  // k-quarter: waves 0..3 handle k = wq*16..+16
    int bin = chunk * 64 + lane;
    bool valid = (bin <= NBINS);
    int rb = valid ? bin : NBINS;       // clamp: stays in-bounds, store is guarded

    float acc[12];
    #pragma unroll
    for (int j = 0; j < 12; j++) acc[j] = 0.0f;
    #pragma unroll
    for (int kk = 0; kk < 16; kk++) {
        int k = wq * 16 + kk;
        float g = g_tT[(size_t)k * BINS1 + rb];   // 64 consecutive floats per wave
        const float* Tl = Tlds + k * 12;          // same addr across lanes -> broadcast
        #pragma unroll
        for (int j = 0; j < 12; j++) acc[j] += g * Tl[j];
    }

    float* pp = part + (size_t)wq * 64 * 13 + (size_t)lane * 13;  // stride 13: conflict-free
    #pragma unroll
    for (int j = 0; j < 12; j++) pp[j] = acc[j];
    __syncthreads();

    const float isc = 1.0f / 64.0f;
    float* svp = sv_table + (size_t)pair * BINS1 * 12 + (size_t)chunk * 64 * 12;
    #pragma unroll
    for (int i = 0; i < 3; i++) {
        int o = tid + 256 * i;          // o = bl*12 + j, bl in [0,64)
        int bl = o / 12;
        int j = o - bl * 12;
        if (chunk * 64 + bl <= NBINS) {
            float s = part[(size_t)0 * 832 + bl * 13 + j]
                    + part[(size_t)1 * 832 + bl * 13 + j]
                    + part[(size_t)2 * 832 + bl * 13 + j]
                    + part[(size_t)3 * 832 + bl * 13 + j];
            svp[o] = s * isc;
        }
    }
    __syncthreads();
}

__device__ __forceinline__ void edge_body(int e,
        const float* __restrict__ pos, const int* __restrict__ batch,
        const int* __restrict__ esrc, const int* __restrict__ edst,
        const float* __restrict__ shifts, const float* __restrict__ cell,
        const int* __restrict__ A,
        const int* __restrict__ node_off, int* __restrict__ node_cur,
        const float* __restrict__ sv_table, float* __restrict__ ef) {
    int s = esrc[e], d = edst[e];
    int slot = atomicAdd(&node_cur[d], 1);       // issued first; latency hides under compute
    int base = node_off[d];                      // independent load, also in flight early

    int gb = batch[s];
    float t0 = shifts[e * 3 + 0], t1 = shifts[e * 3 + 1], t2 = shifts[e * 3 + 2];
    const float* C = cell + gb * 9;
    float shx = t0 * C[0] + t1 * C[3] + t2 * C[6];
    float shy = t0 * C[1] + t1 * C[4] + t2 * C[7];
    float shz = t0 * C[2] + t1 * C[5] + t2 * C[8];
    float ex = pos[d * 3 + 0] - pos[s * 3 + 0] + shx;
    float ey = pos[d * 3 + 1] - pos[s * 3 + 1] + shy;
    float ez = pos[d * 3 + 2] - pos[s * 3 + 2] + shz;
    float r = sqrtf(ex * ex + ey * ey + ez * ez);
    float inv = 1.0f / fmaxf(r, 1e-9f);
    float x = ex * inv, y = ey * inv, z = ez * inv;

    float sv[12];
    if (r >= RMAX) {
        #pragma unroll
        for (int j = 0; j < 12; j++) sv[j] = 0.0f;
    } else {
        int pair = A[s] * 10 + A[d];
        float t = r * ((float)NBINS / RMAX);
        int i = (int)t;
        i = (i > NBINS - 1) ? (NBINS - 1) : i;
        float f = t - (float)i;
        const float* r0 = sv_table + ((size_t)pair * BINS1 + i) * 12;  // 96B contiguous, L2
        #pragma unroll
        for (int j = 0; j < 12; j++) {
            float lo = r0[j], hi = r0[12 + j];
            sv[j] = lo + f * (hi - lo);
        }
    }

    float4* dst = (float4*)(ef + (size_t)(base + slot) * 16);   // 64B aligned
    dst[0] = make_float4(sv[0], sv[1], sv[2],  sv[3]);
    dst[1] = make_float4(sv[4], sv[5], sv[6],  sv[7]);
    dst[2] = make_float4(sv[8], sv[9], sv[10], sv[11]);
    dst[3] = make_float4(x, y, z, 0.0f);
}

__device__ __forceinline__ void gather_body(int t,
        const float* __restrict__ ef, const int* __restrict__ node_off,
        float* __restrict__ out) {
    int n = t >> 3;
    int q = t & 7;
    int beg = node_off[n], end = node_off[n + 1];
    const float4* ef4 = (const float4*)ef;

    const float S3  = 1.7320508075688772f;
    const float S15 = 3.8729833462074170f;
    const float S5  = 2.2360679774997896f;

    float acc[36];
    #pragma unroll
    for (int j = 0; j < 36; j++) acc[j] = 0.0f;

    for (int p = beg + q; p < end; p += 8) {    // lanes q=0..7 cover consecutive rows
        const float4* rp = ef4 + (size_t)p * 4;
        float4 svA = rp[0];
        float4 svB = rp[1];
        float4 svC = rp[2];
        float4 dv  = rp[3];
        float x = dv.x, y = dv.y, z = dv.z;
        float sh1v[3] = { S3 * y, S3 * z, S3 * x };
        float sh2v[5] = { S15 * x * y, S15 * y * z, 0.5f * S5 * (3.0f * z * z - 1.0f),
                          S15 * x * z, 0.5f * S15 * (x * x - y * y) };
        acc[0] += svA.x; acc[1] += svA.y; acc[2] += svA.z; acc[3] += svA.w;
        float bw[4] = { svB.x, svB.y, svB.z, svB.w };
        #pragma unroll
        for (int w = 0; w < 4; w++) {
            #pragma unroll
            for (int j = 0; j < 3; j++) acc[4 + w * 3 + j] += bw[w] * sh1v[j];
        }
        float cw[4] = { svC.x, svC.y, svC.z, svC.w };
        #pragma unroll
        for (int w = 0; w < 4; w++) {
            #pragma unroll
            for (int j = 0; j < 5; j++) acc[16 + w * 5 + j] += cw[w] * sh2v[j];
        }
    }

    #pragma unroll
    for (int j = 0; j < 36; j++) {
        acc[j] += __shfl_xor(acc[j], 1);
        acc[j] += __shfl_xor(acc[j], 2);
        acc[j] += __shfl_xor(acc[j], 4);
    }

    if (q == 0) {
        float c = 1.0f / fmaxf((float)(end - beg), 1.0f);
        float4* o4 = (float4*)out + (size_t)n * 9;
        #pragma unroll
        for (int k = 0; k < 9; k++)
            o4[k] = make_float4(acc[k * 4 + 0] * c, acc[k * 4 + 1] * c,
                                acc[k * 4 + 2] * c, acc[k * 4 + 3] * c);
    }
}

// ===================== fused cooperative kernel (all 4 phases) =======================
__global__ __launch_bounds__(256, 4) void fused_kernel(
        const float* __restrict__ emb,
        const float* __restrict__ fw1, const float* __restrict__ fb1,
        const float* __restrict__ fw2, const float* __restrict__ fb2,
        const float* __restrict__ fw3, const float* __restrict__ fb3,
        const float* __restrict__ fcw1, const float* __restrict__ fcw2,
        const float* __restrict__ fcw3, const float* __restrict__ fcw4,
        const float* __restrict__ pos, const int* __restrict__ batch,
        const int* __restrict__ esrc, const int* __restrict__ edst,
        const float* __restrict__ shifts, const float* __restrict__ cell,
        const int* __restrict__ A,
        float* __restrict__ T, float* __restrict__ g_tT,
        float* __restrict__ sv_table, int* __restrict__ node_off,
        int* __restrict__ cnt_i, int* __restrict__ node_cur,
        float* __restrict__ ef, float* __restrict__ out) {
    cg::grid_group grid = cg::this_grid();
    __shared__ float smem[4096];
    int b = blockIdx.x;
    int tid = threadIdx.x;

    // PHASE A: T build | g-table | histogram (block-strided over 659 tasks)
    for (int bb = b; bb < P1_GRID; bb += FGRID)
        phaseA_body(bb, tid, smem, emb, fw1, fb1, fw2, fb2, fw3, fb3,
                    fcw1, fcw2, fcw3, fcw4, edst, T, g_tT, cnt_i);
    grid.sync();

    // PHASE B: scan | sv_table build (block-strided over 979 tasks)
    for (int bb = b; bb < P2_GRID; bb += FGRID)
        phaseB_body(bb, tid, smem, cnt_i, node_off, T, g_tT, sv_table);
    grid.sync();

    // PHASE C: edge table
    for (int e = b * 256 + tid; e < N_EDGES; e += FGRID * 256)
        edge_body(e, pos, batch, esrc, edst, shifts, cell, A,
                  node_off, node_cur, sv_table, ef);
    grid.sync();

    // PHASE D: gather + mean
    for (int t = b * 256 + tid; t < N_NODES * 8; t += FGRID * 256)
        gather_body(t, ef, node_off, out);
}

// ===================== fallback standalone kernels (round-6 proven path) =============
__global__ __launch_bounds__(256) void prep1_kernel(
        const float* __restrict__ emb,
        const float* __restrict__ fw1, const float* __restrict__ fb1,
        const float* __restrict__ fw2, const float* __restrict__ fb2,
        const float* __restrict__ fw3, const float* __restrict__ fb3,
        const float* __restrict__ fcw1, const float* __restrict__ fcw2,
        const float* __restrict__ fcw3, const float* __restrict__ fcw4,
        const int* __restrict__ edst,
        float* __restrict__ T, float* __restrict__ g_tT,
        int* __restrict__ cnt_i) {
    __shared__ float smem[4096];
    phaseA_body(blockIdx.x, threadIdx.x, smem, emb, fw1, fb1, fw2, fb2, fw3, fb3,
                fcw1, fcw2, fcw3, fcw4, edst, T, g_tT, cnt_i);
}

__global__ __launch_bounds__(256) void prep2_kernel(
        const int* __restrict__ cnt_i, int* __restrict__ node_off,
        const float* __restrict__ T, const float* __restrict__ g_tT,
        float* __restrict__ sv_table) {
    __shared__ float smem[4096];
    phaseB_body(blockIdx.x, threadIdx.x, smem, cnt_i, node_off, T, g_tT, sv_table);
}

__global__ __launch_bounds__(256) void edge_table_kernel(
        const float* __restrict__ pos, const int* __restrict__ batch,
        const int* __restrict__ esrc, const int* __restrict__ edst,
        const float* __restrict__ shifts, const float* __restrict__ cell,
        const int* __restrict__ A,
        const int* __restrict__ node_off, int* __restrict__ node_cur,
        const float* __restrict__ sv_table, float* __restrict__ ef) {
    int e = blockIdx.x * 256 + threadIdx.x;
    if (e >= N_EDGES) return;
    edge_body(e, pos, batch, esrc, edst, shifts, cell, A,
              node_off, node_cur, sv_table, ef);
}

__global__ __launch_bounds__(256) void gather_kernel(const float* __restrict__ ef,
                                                     const int* __restrict__ node_off,
                                                     float* __restrict__ out) {
    int t = blockIdx.x * 256 + threadIdx.x;
    if (t >= N_NODES * 8) return;
    gather_body(t, ef, node_off, out);
}

extern "C" void kernel_launch(void* const* d_in, const int* in_sizes, int n_in,
                              void* d_out, int out_size, void* d_ws, size_t ws_size,
                              hipStream_t stream) {
    const float* pos    = (const float*)d_in[0];
    const int*   A      = (const int*)d_in[1];
    const int*   batch  = (const int*)d_in[2];
    const int*   esrc   = (const int*)d_in[3];
    const int*   edst   = (const int*)d_in[4];
    const float* shifts = (const float*)d_in[5];
    const float* cell   = (const float*)d_in[6];
    const float* emb    = (const float*)d_in[7];
    const float* fw1    = (const float*)d_in[8];
    const float* fb1    = (const float*)d_in[9];
    const float* fw2    = (const float*)d_in[10];
    const float* fb2    = (const float*)d_in[11];
    const float* fw3    = (const float*)d_in[12];
    const float* fb3    = (const float*)d_in[13];
    const float* fcw1   = (const float*)d_in[14];
    const float* fcw2   = (const float*)d_in[15];
    const float* fcw3   = (const float*)d_in[16];
    const float* fcw4   = (const float*)d_in[17];
    float* out = (float*)d_out;

    char* ws = (char*)d_ws;
    float* ef      = (float*)(ws + OFF_EF);
    float* T       = (float*)(ws + OFF_T);
    float* g_tT    = (float*)(ws + OFF_G);
    float* sv_table= (float*)(ws + OFF_SV);
    int*   node_off= (int*)(ws + OFF_NOFF);
    int*   cnt_i   = (int*)(ws + OFF_NCNT);
    int*   node_cur= (int*)(ws + OFF_NCUR);

    hipMemsetAsync(cnt_i, 0, (size_t)2 * N_NODES * 4, stream);

    void* args[] = {
        (void*)&emb, (void*)&fw1, (void*)&fb1, (void*)&fw2, (void*)&fb2,
        (void*)&fw3, (void*)&fb3, (void*)&fcw1, (void*)&fcw2, (void*)&fcw3,
        (void*)&fcw4, (void*)&pos, (void*)&batch, (void*)&esrc, (void*)&edst,
        (void*)&shifts, (void*)&cell, (void*)&A, (void*)&T, (void*)&g_tT,
        (void*)&sv_table, (void*)&node_off, (void*)&cnt_i, (void*)&node_cur,
        (void*)&ef, (void*)&out
    };
    hipError_t err = hipLaunchCooperativeKernel((const void*)fused_kernel,
                                                dim3(FGRID), dim3(256),
                                                args, 0, stream);
    if (err != hipSuccess) {
        // fallback: proven 4-kernel path (round 6)
        prep1_kernel<<<P1_GRID, 256, 0, stream>>>(emb, fw1, fb1, fw2, fb2, fw3, fb3,
                                                  fcw1, fcw2, fcw3, fcw4, edst,
                                                  T, g_tT, cnt_i);
        prep2_kernel<<<P2_GRID, 256, 0, stream>>>(cnt_i, node_off, T, g_tT, sv_table);
        edge_table_kernel<<<(N_EDGES + 255) / 256, 256, 0, stream>>>(
            pos, batch, esrc, edst, shifts, cell, A, node_off, node_cur, sv_table, ef);
        gather_kernel<<<(N_NODES * 8 + 255) / 256, 256, 0, stream>>>(ef, node_off, out);
    }
}

// Round 8
// 159.086 us; speedup vs baseline: 2.8885x; 2.8885x over previous
//
#include <hip/hip_runtime.h>
#include <math.h>

#define N_NODES 20000
#define N_EDGES 160000

#define NBINS   512                  // usable bins; bin 512 = endpoint r=7.5 (sv==0 there exactly)
#define BINS1   513                  // rows stored per pair
#define RMAX    7.5f

// ws layout (bytes). ~13.8 MB.
// ef rows are COMPACT: 16 floats = {sv[12], x, y, z, pad} = 64B, one cacheline/edge.
static const size_t OFF_EF  = 0;                                     // ef [E][16] f32 (node-grouped rows)
static const size_t OFF_T   = OFF_EF  + (size_t)N_EDGES * 16 * 4;    // T [100][64][12]
static const size_t OFF_G   = OFF_T   + (size_t)100 * 64 * 12 * 4;   // g_tT [64][513] (k-major)
static const size_t OFF_SV  = OFF_G   + (size_t)64 * BINS1 * 4;      // sv_table [100][513][12]
static const size_t OFF_NOFF= OFF_SV  + (size_t)100 * BINS1 * 12 * 4;// node_off [N+1] int
static const size_t OFF_NCNT= OFF_NOFF+ (size_t)(N_NODES + 1) * 4;   // cnt_i [N] int (zeroed)
static const size_t OFF_RANK= OFF_NCNT+ (size_t)N_NODES * 4;         // rank [E] int (slot per edge)

// prep1 grid split: [0,25) ai+T build, [25,34) g-table (64 bins/block), [34,659) histogram
#define P1_T_BLOCKS  25
#define P1_G_BLOCKS  9
#define P1_H_BLOCKS  625
#define P1_GRID (P1_T_BLOCKS + P1_G_BLOCKS + P1_H_BLOCKS)
// prep2 grid: [0,79) parallel scan (256 nodes/block, base = direct coalesced prefix sum);
//             [79, 79+900) sv build
#define P2_SCAN_BLOCKS 79
#define P2_CHUNKS 9
#define P2_GRID (P2_SCAN_BLOCKS + 100 * P2_CHUNKS)

__device__ __forceinline__ float silu_f(float x) {
    return x / (1.0f + __expf(-x));
}

// ---------------- K1: prep1 — ai+T build | g-table (cooperative) | histogram+rank ----
__global__ __launch_bounds__(256) void prep1_kernel(
        const float* __restrict__ emb,
        const float* __restrict__ fw1, const float* __restrict__ fb1,
        const float* __restrict__ fw2, const float* __restrict__ fb2,
        const float* __restrict__ fw3, const float* __restrict__ fb3,
        const float* __restrict__ fc_w1, const float* __restrict__ fc_w2,
        const float* __restrict__ fc_w3, const float* __restrict__ fc_w4,
        const int* __restrict__ edst,
        float* __restrict__ T, float* __restrict__ g_tT,
        int* __restrict__ cnt_i, int* __restrict__ rank_e) {
    __shared__ float smem[4096];        // T-branch uses 1040; g-branch uses 4096
    int b = blockIdx.x;
    int tid = threadIdx.x;

    if (b < P1_T_BLOCKS) {
        // ---- inline node-type MLP (10 types) then T[pair][k][12] build ----
        float* h1s = smem;              // [10][64]
        float* h2s = smem + 640;        // [10][32]
        float* ai  = smem + 960;        // [10][8]
        for (int idx = tid; idx < 640; idx += 256) {
            int t = idx >> 6, j = idx & 63;
            float acc = fb1[j];
            #pragma unroll
            for (int i = 0; i < 16; i++) acc += emb[t * 16 + i] * fw1[i * 64 + j];
            h1s[idx] = silu_f(acc);
        }
        __syncthreads();
        for (int idx = tid; idx < 320; idx += 256) {
            int t = idx >> 5, j = idx & 31;
            float acc = fb2[j];
            #pragma unroll
            for (int i = 0; i < 64; i++) acc += h1s[t * 64 + i] * fw2[i * 32 + j];
            h2s[idx] = silu_f(acc);
        }
        __syncthreads();
        if (tid < 80) {
            int t = tid >> 3, j = tid & 7;
            float acc = fb3[j];
            #pragma unroll
            for (int i = 0; i < 32; i++) acc += h2s[t * 32 + i] * fw3[i * 8 + j];
            ai[tid] = acc;
        }
        __syncthreads();

        int idx = b * 256 + tid;        // 6400 = 100 pairs x 64 k
        int pair = idx >> 6;
        int k = idx & 63;
        int ts = pair / 10, td = pair - ts * 10;
        float a[8], bb[8];
        #pragma unroll
        for (int i = 0; i < 8; i++) a[i] = ai[ts * 8 + i];
        #pragma unroll
        for (int i = 0; i < 8; i++) bb[i] = ai[td * 8 + i];
        float sv[12];
        #pragma unroll
        for (int i = 0; i < 12; i++) sv[i] = 0.0f;
        const float* wk = fc_w4 + k * 768;
        #pragma unroll 2
        for (int u = 0; u < 8; u++) {
            #pragma unroll
            for (int v = 0; v < 8; v++) {
                float ab = a[u] * bb[v];
                const float* wp = wk + u * 32 + v * 4;
                float4 w0 = *(const float4*)(wp);
                float4 w1 = *(const float4*)(wp + 256);
                float4 w2 = *(const float4*)(wp + 512);
                sv[0] += ab * w0.x; sv[1] += ab * w0.y; sv[2]  += ab * w0.z; sv[3]  += ab * w0.w;
                sv[4] += ab * w1.x; sv[5] += ab * w1.y; sv[6]  += ab * w1.z; sv[7]  += ab * w1.w;
                sv[8] += ab * w2.x; sv[9] += ab * w2.y; sv[10] += ab * w2.z; sv[11] += ab * w2.w;
            }
        }
        float* tp = T + pair * 768 + k * 12;
        #pragma unroll
        for (int j = 0; j < 12; j++) tp[j] = sv[j];
    } else if (b < P1_T_BLOCKS + P1_G_BLOCKS) {
        // ---- g-table, cooperative: 64 bins/block (lane=bin), wave owns 16 channels ----
        int lane = tid & 63;
        int wq = __builtin_amdgcn_readfirstlane(tid >> 6);
        int bin = (b - P1_T_BLOCKS) * 64 + lane;
        bool valid = (bin <= NBINS);
        float r = (float)bin * (RMAX / (float)NBINS);

        float rb[16];
        const float step = 5.0f / 17.0f;
        const float istep = 17.0f / 5.0f;
        const float rsc = 4.0f / 1.12f;
        #pragma unroll
        for (int i = 0; i < 16; i++) {
            float dd = (r - (float)(i + 1) * step) * istep;
            rb[i] = __expf(-dd * dd) * rsc;
        }

        // L1: 16 -> 64 (weight addresses wave-uniform -> scalar loads)
        #pragma unroll
        for (int jj = 0; jj < 16; jj++) {
            int j = wq * 16 + jj;
            float a0 = 0, a1 = 0, a2 = 0, a3 = 0;
            #pragma unroll
            for (int i = 0; i < 16; i += 4) {
                a0 += rb[i]     * fc_w1[(i)     * 64 + j];
                a1 += rb[i + 1] * fc_w1[(i + 1) * 64 + j];
                a2 += rb[i + 2] * fc_w1[(i + 2) * 64 + j];
                a3 += rb[i + 3] * fc_w1[(i + 3) * 64 + j];
            }
            smem[j * 64 + lane] = silu_f(((a0 + a1) + (a2 + a3)) * 0.25f);
        }
        __syncthreads();

        // L2: 64 -> 64
        float acc[16];
        #pragma unroll
        for (int jj = 0; jj < 16; jj++) acc[jj] = 0.0f;
        #pragma unroll
        for (int c = 0; c < 4; c++) {
            float hc[16];
            #pragma unroll
            for (int i = 0; i < 16; i++) hc[i] = smem[(c * 16 + i) * 64 + lane];
            #pragma unroll
            for (int jj = 0; jj < 16; jj++) {
                int j = wq * 16 + jj;
                #pragma unroll
                for (int i = 0; i < 16; i++) acc[jj] += hc[i] * fc_w2[(c * 16 + i) * 64 + j];
            }
        }
        __syncthreads();
        #pragma unroll
        for (int jj = 0; jj < 16; jj++) smem[(wq * 16 + jj) * 64 + lane] = silu_f(acc[jj] * 0.125f);
        __syncthreads();

        // L3: 64 -> 64 -> g_tT[k][bin] (lane-coalesced stores)
        #pragma unroll
        for (int jj = 0; jj < 16; jj++) acc[jj] = 0.0f;
        #pragma unroll
        for (int c = 0; c < 4; c++) {
            float hc[16];
            #pragma unroll
            for (int i = 0; i < 16; i++) hc[i] = smem[(c * 16 + i) * 64 + lane];
            #pragma unroll
            for (int jj = 0; jj < 16; jj++) {
                int j = wq * 16 + jj;
                #pragma unroll
                for (int i = 0; i < 16; i++) acc[jj] += hc[i] * fc_w3[(c * 16 + i) * 64 + j];
            }
        }
        if (valid) {
            #pragma unroll
            for (int jj = 0; jj < 16; jj++)
                g_tT[(size_t)(wq * 16 + jj) * BINS1 + bin] = silu_f(acc[jj] * 0.125f);
        }
    } else {
        // ---- histogram of edge_dst; the returned old count IS the edge's CSR slot ----
        // (moves the returning atomic out of the edge kernel's dependent chain)
        int e = (b - P1_T_BLOCKS - P1_G_BLOCKS) * 256 + tid;
        if (e < N_EDGES) rank_e[e] = atomicAdd(&cnt_i[edst[e]], 1);
    }
}

// ---------------- K2: prep2 — parallel scan | sv_table build -------------------------
// Scan: 79 independent blocks, 256 nodes each. Block base = direct sum of
// cnt_i[0 .. 256b) via striped coalesced loads (L2-resident 80KB, pipelined) +
// block shfl reduce. No inter-block sync. node_off[N_NODES] == N_EDGES is constant.
__global__ __launch_bounds__(256) void prep2_kernel(
        const int* __restrict__ cnt_i, int* __restrict__ node_off,
        const float* __restrict__ T, const float* __restrict__ g_tT,
        float* __restrict__ sv_table) {
    __shared__ float smem[4096];        // scan: wred[4]+wsum[4] | sv: part+Tlds
    int b = blockIdx.x;
    int tid = threadIdx.x;

    if (b < P2_SCAN_BLOCKS) {
        int* wred = (int*)smem;         // [4] base partial reduce
        int* wsum = (int*)smem + 4;     // [4] per-wave scan totals
        int lane = tid & 63, w = tid >> 6;
        int nbase = b * 256;
        int n = nbase + tid;
        int c = (n < N_NODES) ? cnt_i[n] : 0;        // coalesced

        // base = sum cnt_i[0..nbase): striped coalesced loads, independent -> pipelined
        int part = 0;
        for (int i = tid; i < nbase; i += 256) part += cnt_i[i];
        #pragma unroll
        for (int off = 1; off < 64; off <<= 1) part += __shfl_xor(part, off);
        if (lane == 0) wred[w] = part;

        // wave-inclusive scan of c (independent of the base reduce)
        int sc = c;
        #pragma unroll
        for (int off = 1; off < 64; off <<= 1) {
            int v2 = __shfl_up(sc, off);
            if (lane >= off) sc += v2;
        }
        if (lane == 63) wsum[w] = sc;
        __syncthreads();

        int base = wred[0] + wred[1] + wred[2] + wred[3];
        int wb = 0;
        #pragma unroll
        for (int i = 0; i < 4; i++) wb += (i < w) ? wsum[i] : 0;
        if (n < N_NODES) node_off[n] = base + wb + (sc - c);   // exclusive, coalesced
        if (b == 0 && tid == 0) node_off[N_NODES] = N_EDGES;
        return;
    }

    int idx = b - P2_SCAN_BLOCKS;
    int pair = idx / P2_CHUNKS;
    int chunk = idx - pair * P2_CHUNKS;

    float* part = smem;                 // [4][64][13]
    float* Tlds = smem + 3328;          // [768]

    // stage T[pair][64][12] -> LDS (coalesced, 3 floats/thread)
    const float* Tp = T + pair * 768;
    #pragma unroll
    for (int i = tid; i < 768; i += 256) Tlds[i] = Tp[i];
    __syncthreads();

    int lane = tid & 63;                // bin within chunk
    int wq = tid >> 6;                  // k-quarter: waves 0..3 handle k = wq*16..+16
    int bin = chunk * 64 + lane;
    bool valid = (bin <= NBINS);
    int rb = valid ? bin : NBINS;       // clamp: stays in-bounds, store is guarded

    float acc[12];
    #pragma unroll
    for (int j = 0; j < 12; j++) acc[j] = 0.0f;
    #pragma unroll
    for (int kk = 0; kk < 16; kk++) {
        int k = wq * 16 + kk;
        float g = g_tT[(size_t)k * BINS1 + rb];   // 64 consecutive floats per wave
        const float* Tl = Tlds + k * 12;          // same addr across lanes -> broadcast
        #pragma unroll
        for (int j = 0; j < 12; j++) acc[j] += g * Tl[j];
    }

    float* pp = part + (size_t)wq * 64 * 13 + (size_t)lane * 13;  // stride 13: conflict-free
    #pragma unroll
    for (int j = 0; j < 12; j++) pp[j] = acc[j];
    __syncthreads();

    // final reduce + store: 768 outputs, 3 per thread, coalesced
    const float isc = 1.0f / 64.0f;
    float* svp = sv_table + (size_t)pair * BINS1 * 12 + (size_t)chunk * 64 * 12;
    #pragma unroll
    for (int i = 0; i < 3; i++) {
        int o = tid + 256 * i;          // o = bl*12 + j, bl in [0,64)
        int bl = o / 12;
        int j = o - bl * 12;
        if (chunk * 64 + bl <= NBINS) {
            float s = part[(size_t)0 * 832 + bl * 13 + j]
                    + part[(size_t)1 * 832 + bl * 13 + j]
                    + part[(size_t)2 * 832 + bl * 13 + j]
                    + part[(size_t)3 * 832 + bl * 13 + j];
            svp[o] = s * isc;
        }
    }
}

// ---------------- K3: edge kernel — compact 64B row, NO atomic (precomputed rank) -----
__global__ __launch_bounds__(256) void edge_table_kernel(
        const float* __restrict__ pos, const int* __restrict__ batch,
        const int* __restrict__ esrc, const int* __restrict__ edst,
        const float* __restrict__ shifts, const float* __restrict__ cell,
        const int* __restrict__ A,
        const int* __restrict__ node_off, const int* __restrict__ rank_e,
        const float* __restrict__ sv_table, float* __restrict__ ef) {
    int e = blockIdx.x * 256 + threadIdx.x;
    if (e >= N_EDGES) return;

    int s = esrc[e], d = edst[e];
    int slot = rank_e[e];                        // coalesced load, no atomic round-trip
    int base = node_off[d];                      // independent L2 load, in flight early

    int gb = batch[s];
    float t0 = shifts[e * 3 + 0], t1 = shifts[e * 3 + 1], t2 = shifts[e * 3 + 2];
    const float* C = cell + gb * 9;
    float shx = t0 * C[0] + t1 * C[3] + t2 * C[6];
    float shy = t0 * C[1] + t1 * C[4] + t2 * C[7];
    float shz = t0 * C[2] + t1 * C[5] + t2 * C[8];
    float ex = pos[d * 3 + 0] - pos[s * 3 + 0] + shx;
    float ey = pos[d * 3 + 1] - pos[s * 3 + 1] + shy;
    float ez = pos[d * 3 + 2] - pos[s * 3 + 2] + shz;
    float r = sqrtf(ex * ex + ey * ey + ez * ez);
    float inv = 1.0f / fmaxf(r, 1e-9f);
    float x = ex * inv, y = ey * inv, z = ez * inv;

    float sv[12];
    if (r >= RMAX) {
        #pragma unroll
        for (int j = 0; j < 12; j++) sv[j] = 0.0f;
    } else {
        int pair = A[s] * 10 + A[d];
        float t = r * ((float)NBINS / RMAX);
        int i = (int)t;
        i = (i > NBINS - 1) ? (NBINS - 1) : i;
        float f = t - (float)i;
        const float* r0 = sv_table + ((size_t)pair * BINS1 + i) * 12;  // 96B contiguous, L2
        #pragma unroll
        for (int j = 0; j < 12; j++) {
            float lo = r0[j], hi = r0[12 + j];
            sv[j] = lo + f * (hi - lo);
        }
    }

    float4* dst = (float4*)(ef + (size_t)(base + slot) * 16);   // 64B aligned
    dst[0] = make_float4(sv[0], sv[1], sv[2],  sv[3]);
    dst[1] = make_float4(sv[4], sv[5], sv[6],  sv[7]);
    dst[2] = make_float4(sv[8], sv[9], sv[10], sv[11]);
    dst[3] = make_float4(x, y, z, 0.0f);
}

// ---------------- K4: gather — 8 threads/node, reconstruct sv x sh, shfl reduce -------
__global__ __launch_bounds__(256) void gather_kernel(const float* __restrict__ ef,
                                                     const int* __restrict__ node_off,
                                                     float* __restrict__ out) {
    int t = blockIdx.x * 256 + threadIdx.x;     // (node, eighth)
    if (t >= N_NODES * 8) return;
    int n = t >> 3;
    int q = t & 7;
    int beg = node_off[n], end = node_off[n + 1];
    const float4* ef4 = (const float4*)ef;

    const float S3  = 1.7320508075688772f;
    const float S15 = 3.8729833462074170f;
    const float S5  = 2.2360679774997896f;

    float acc[36];
    #pragma unroll
    for (int j = 0; j < 36; j++) acc[j] = 0.0f;

    for (int p = beg + q; p < end; p += 8) {    // lanes q=0..7 cover consecutive rows
        const float4* rp = ef4 + (size_t)p * 4;
        float4 svA = rp[0];
        float4 svB = rp[1];
        float4 svC = rp[2];
        float4 dv  = rp[3];
        float x = dv.x, y = dv.y, z = dv.z;
        float sh1v[3] = { S3 * y, S3 * z, S3 * x };
        float sh2v[5] = { S15 * x * y, S15 * y * z, 0.5f * S5 * (3.0f * z * z - 1.0f),
                          S15 * x * z, 0.5f * S15 * (x * x - y * y) };
        acc[0] += svA.x; acc[1] += svA.y; acc[2] += svA.z; acc[3] += svA.w;
        float bw[4] = { svB.x, svB.y, svB.z, svB.w };
        #pragma unroll
        for (int w = 0; w < 4; w++) {
            #pragma unroll
            for (int j = 0; j < 3; j++) acc[4 + w * 3 + j] += bw[w] * sh1v[j];
        }
        float cw[4] = { svC.x, svC.y, svC.z, svC.w };
        #pragma unroll
        for (int w = 0; w < 4; w++) {
            #pragma unroll
            for (int j = 0; j < 5; j++) acc[16 + w * 5 + j] += cw[w] * sh2v[j];
        }
    }

    // reduce the 8 per-node threads (same wave: 8 | 64)
    #pragma unroll
    for (int j = 0; j < 36; j++) {
        acc[j] += __shfl_xor(acc[j], 1);
        acc[j] += __shfl_xor(acc[j], 2);
        acc[j] += __shfl_xor(acc[j], 4);
    }

    if (q == 0) {
        float c = 1.0f / fmaxf((float)(end - beg), 1.0f);
        float4* o4 = (float4*)out + (size_t)n * 9;
        #pragma unroll
        for (int k = 0; k < 9; k++)
            o4[k] = make_float4(acc[k * 4 + 0] * c, acc[k * 4 + 1] * c,
                                acc[k * 4 + 2] * c, acc[k * 4 + 3] * c);
    }
}

extern "C" void kernel_launch(void* const* d_in, const int* in_sizes, int n_in,
                              void* d_out, int out_size, void* d_ws, size_t ws_size,
                              hipStream_t stream) {
    const float* pos    = (const float*)d_in[0];
    const int*   A      = (const int*)d_in[1];
    const int*   batch  = (const int*)d_in[2];
    const int*   esrc   = (const int*)d_in[3];
    const int*   edst   = (const int*)d_in[4];
    const float* shifts = (const float*)d_in[5];
    const float* cell   = (const float*)d_in[6];
    const float* emb    = (const float*)d_in[7];
    const float* fw1    = (const float*)d_in[8];
    const float* fb1    = (const float*)d_in[9];
    const float* fw2    = (const float*)d_in[10];
    const float* fb2    = (const float*)d_in[11];
    const float* fw3    = (const float*)d_in[12];
    const float* fb3    = (const float*)d_in[13];
    const float* fcw1   = (const float*)d_in[14];
    const float* fcw2   = (const float*)d_in[15];
    const float* fcw3   = (const float*)d_in[16];
    const float* fcw4   = (const float*)d_in[17];
    float* out = (float*)d_out;

    char* ws = (char*)d_ws;
    float* ef      = (float*)(ws + OFF_EF);
    float* T       = (float*)(ws + OFF_T);
    float* g_tT    = (float*)(ws + OFF_G);
    float* sv_table= (float*)(ws + OFF_SV);
    int*   node_off= (int*)(ws + OFF_NOFF);
    int*   cnt_i   = (int*)(ws + OFF_NCNT);
    int*   rank_e  = (int*)(ws + OFF_RANK);

    hipMemsetAsync(cnt_i, 0, (size_t)N_NODES * 4, stream);

    prep1_kernel<<<P1_GRID, 256, 0, stream>>>(emb, fw1, fb1, fw2, fb2, fw3, fb3,
                                              fcw1, fcw2, fcw3, fcw4, edst,
                                              T, g_tT, cnt_i, rank_e);
    prep2_kernel<<<P2_GRID, 256, 0, stream>>>(cnt_i, node_off, T, g_tT, sv_table);
    edge_table_kernel<<<(N_EDGES + 255) / 256, 256, 0, stream>>>(
        pos, batch, esrc, edst, shifts, cell, A, node_off, rank_e, sv_table, ef);
    gather_kernel<<<(N_NODES * 8 + 255) / 256, 256, 0, stream>>>(ef, node_off, out);
}

// Round 9
// 157.330 us; speedup vs baseline: 2.9207x; 1.0112x over previous
//
#include <hip/hip_runtime.h>
#include <math.h>

#define N_NODES 20000
#define N_EDGES 160000

#define NBINS   512                  // usable bins; bin 512 = endpoint r=7.5 (sv==0 there exactly)
#define BINS1   513                  // rows stored per pair
#define RMAX    7.5f

// ws layout (bytes). ~4.3 MB (ef buffer eliminated).
static const size_t OFF_T   = 0;                                     // T [100][64][12]
static const size_t OFF_G   = OFF_T   + (size_t)100 * 64 * 12 * 4;   // g_tT [64][513] (k-major)
static const size_t OFF_SV  = OFF_G   + (size_t)64 * BINS1 * 4;      // sv_table [100][513][12]
static const size_t OFF_NOFF= OFF_SV  + (size_t)100 * BINS1 * 12 * 4;// node_off [N+1] int
static const size_t OFF_NCNT= OFF_NOFF+ (size_t)(N_NODES + 1) * 4;   // cnt_i [N] int (zeroed)
static const size_t OFF_RANK= OFF_NCNT+ (size_t)N_NODES * 4;         // rank [E] int (slot per edge)
static const size_t OFF_CSR = OFF_RANK+ (size_t)N_EDGES * 4;         // csr_eid [E] int

// prep1 grid split: [0,25) ai+T build, [25,34) g-table (64 bins/block), [34,659) histogram
#define P1_T_BLOCKS  25
#define P1_G_BLOCKS  9
#define P1_H_BLOCKS  625
#define P1_GRID (P1_T_BLOCKS + P1_G_BLOCKS + P1_H_BLOCKS)
// prep2 grid: [0,79) parallel scan (256 nodes/block); [79, 79+900) sv build
#define P2_SCAN_BLOCKS 79
#define P2_CHUNKS 9
#define P2_GRID (P2_SCAN_BLOCKS + 100 * P2_CHUNKS)

__device__ __forceinline__ float silu_f(float x) {
    return x / (1.0f + __expf(-x));
}

// ---------------- K1: prep1 — ai+T build | g-table (cooperative) | histogram+rank ----
__global__ __launch_bounds__(256) void prep1_kernel(
        const float* __restrict__ emb,
        const float* __restrict__ fw1, const float* __restrict__ fb1,
        const float* __restrict__ fw2, const float* __restrict__ fb2,
        const float* __restrict__ fw3, const float* __restrict__ fb3,
        const float* __restrict__ fc_w1, const float* __restrict__ fc_w2,
        const float* __restrict__ fc_w3, const float* __restrict__ fc_w4,
        const int* __restrict__ edst,
        float* __restrict__ T, float* __restrict__ g_tT,
        int* __restrict__ cnt_i, int* __restrict__ rank_e) {
    __shared__ float smem[4096];        // T-branch uses 1040; g-branch uses 4096
    int b = blockIdx.x;
    int tid = threadIdx.x;

    if (b < P1_T_BLOCKS) {
        // ---- inline node-type MLP (10 types) then T[pair][k][12] build ----
        float* h1s = smem;              // [10][64]
        float* h2s = smem + 640;        // [10][32]
        float* ai  = smem + 960;        // [10][8]
        for (int idx = tid; idx < 640; idx += 256) {
            int t = idx >> 6, j = idx & 63;
            float acc = fb1[j];
            #pragma unroll
            for (int i = 0; i < 16; i++) acc += emb[t * 16 + i] * fw1[i * 64 + j];
            h1s[idx] = silu_f(acc);
        }
        __syncthreads();
        for (int idx = tid; idx < 320; idx += 256) {
            int t = idx >> 5, j = idx & 31;
            float acc = fb2[j];
            #pragma unroll
            for (int i = 0; i < 64; i++) acc += h1s[t * 64 + i] * fw2[i * 32 + j];
            h2s[idx] = silu_f(acc);
        }
        __syncthreads();
        if (tid < 80) {
            int t = tid >> 3, j = tid & 7;
            float acc = fb3[j];
            #pragma unroll
            for (int i = 0; i < 32; i++) acc += h2s[t * 32 + i] * fw3[i * 8 + j];
            ai[tid] = acc;
        }
        __syncthreads();

        int idx = b * 256 + tid;        // 6400 = 100 pairs x 64 k
        int pair = idx >> 6;
        int k = idx & 63;
        int ts = pair / 10, td = pair - ts * 10;
        float a[8], bb[8];
        #pragma unroll
        for (int i = 0; i < 8; i++) a[i] = ai[ts * 8 + i];
        #pragma unroll
        for (int i = 0; i < 8; i++) bb[i] = ai[td * 8 + i];
        float sv[12];
        #pragma unroll
        for (int i = 0; i < 12; i++) sv[i] = 0.0f;
        const float* wk = fc_w4 + k * 768;
        #pragma unroll 2
        for (int u = 0; u < 8; u++) {
            #pragma unroll
            for (int v = 0; v < 8; v++) {
                float ab = a[u] * bb[v];
                const float* wp = wk + u * 32 + v * 4;
                float4 w0 = *(const float4*)(wp);
                float4 w1 = *(const float4*)(wp + 256);
                float4 w2 = *(const float4*)(wp + 512);
                sv[0] += ab * w0.x; sv[1] += ab * w0.y; sv[2]  += ab * w0.z; sv[3]  += ab * w0.w;
                sv[4] += ab * w1.x; sv[5] += ab * w1.y; sv[6]  += ab * w1.z; sv[7]  += ab * w1.w;
                sv[8] += ab * w2.x; sv[9] += ab * w2.y; sv[10] += ab * w2.z; sv[11] += ab * w2.w;
            }
        }
        float* tp = T + pair * 768 + k * 12;
        #pragma unroll
        for (int j = 0; j < 12; j++) tp[j] = sv[j];
    } else if (b < P1_T_BLOCKS + P1_G_BLOCKS) {
        // ---- g-table, cooperative: 64 bins/block (lane=bin), wave owns 16 channels ----
        int lane = tid & 63;
        int wq = __builtin_amdgcn_readfirstlane(tid >> 6);
        int bin = (b - P1_T_BLOCKS) * 64 + lane;
        bool valid = (bin <= NBINS);
        float r = (float)bin * (RMAX / (float)NBINS);

        float rb[16];
        const float step = 5.0f / 17.0f;
        const float istep = 17.0f / 5.0f;
        const float rsc = 4.0f / 1.12f;
        #pragma unroll
        for (int i = 0; i < 16; i++) {
            float dd = (r - (float)(i + 1) * step) * istep;
            rb[i] = __expf(-dd * dd) * rsc;
        }

        // L1: 16 -> 64 (weight addresses wave-uniform -> scalar loads)
        #pragma unroll
        for (int jj = 0; jj < 16; jj++) {
            int j = wq * 16 + jj;
            float a0 = 0, a1 = 0, a2 = 0, a3 = 0;
            #pragma unroll
            for (int i = 0; i < 16; i += 4) {
                a0 += rb[i]     * fc_w1[(i)     * 64 + j];
                a1 += rb[i + 1] * fc_w1[(i + 1) * 64 + j];
                a2 += rb[i + 2] * fc_w1[(i + 2) * 64 + j];
                a3 += rb[i + 3] * fc_w1[(i + 3) * 64 + j];
            }
            smem[j * 64 + lane] = silu_f(((a0 + a1) + (a2 + a3)) * 0.25f);
        }
        __syncthreads();

        // L2: 64 -> 64
        float acc[16];
        #pragma unroll
        for (int jj = 0; jj < 16; jj++) acc[jj] = 0.0f;
        #pragma unroll
        for (int c = 0; c < 4; c++) {
            float hc[16];
            #pragma unroll
            for (int i = 0; i < 16; i++) hc[i] = smem[(c * 16 + i) * 64 + lane];
            #pragma unroll
            for (int jj = 0; jj < 16; jj++) {
                int j = wq * 16 + jj;
                #pragma unroll
                for (int i = 0; i < 16; i++) acc[jj] += hc[i] * fc_w2[(c * 16 + i) * 64 + j];
            }
        }
        __syncthreads();
        #pragma unroll
        for (int jj = 0; jj < 16; jj++) smem[(wq * 16 + jj) * 64 + lane] = silu_f(acc[jj] * 0.125f);
        __syncthreads();

        // L3: 64 -> 64 -> g_tT[k][bin] (lane-coalesced stores)
        #pragma unroll
        for (int jj = 0; jj < 16; jj++) acc[jj] = 0.0f;
        #pragma unroll
        for (int c = 0; c < 4; c++) {
            float hc[16];
            #pragma unroll
            for (int i = 0; i < 16; i++) hc[i] = smem[(c * 16 + i) * 64 + lane];
            #pragma unroll
            for (int jj = 0; jj < 16; jj++) {
                int j = wq * 16 + jj;
                #pragma unroll
                for (int i = 0; i < 16; i++) acc[jj] += hc[i] * fc_w3[(c * 16 + i) * 64 + j];
            }
        }
        if (valid) {
            #pragma unroll
            for (int jj = 0; jj < 16; jj++)
                g_tT[(size_t)(wq * 16 + jj) * BINS1 + bin] = silu_f(acc[jj] * 0.125f);
        }
    } else {
        // ---- histogram of edge_dst; the returned old count IS the edge's CSR slot ----
        int e = (b - P1_T_BLOCKS - P1_G_BLOCKS) * 256 + tid;
        if (e < N_EDGES) rank_e[e] = atomicAdd(&cnt_i[edst[e]], 1);
    }
}

// ---------------- K2: prep2 — parallel scan | sv_table build -------------------------
__global__ __launch_bounds__(256) void prep2_kernel(
        const int* __restrict__ cnt_i, int* __restrict__ node_off,
        const float* __restrict__ T, const float* __restrict__ g_tT,
        float* __restrict__ sv_table) {
    __shared__ float smem[4096];        // scan: wred[4]+wsum[4] | sv: part+Tlds
    int b = blockIdx.x;
    int tid = threadIdx.x;

    if (b < P2_SCAN_BLOCKS) {
        int* wred = (int*)smem;         // [4] base partial reduce
        int* wsum = (int*)smem + 4;     // [4] per-wave scan totals
        int lane = tid & 63, w = tid >> 6;
        int nbase = b * 256;
        int n = nbase + tid;
        int c = (n < N_NODES) ? cnt_i[n] : 0;        // coalesced

        // base = sum cnt_i[0..nbase): striped coalesced loads, independent -> pipelined
        int part = 0;
        for (int i = tid; i < nbase; i += 256) part += cnt_i[i];
        #pragma unroll
        for (int off = 1; off < 64; off <<= 1) part += __shfl_xor(part, off);
        if (lane == 0) wred[w] = part;

        // wave-inclusive scan of c (independent of the base reduce)
        int sc = c;
        #pragma unroll
        for (int off = 1; off < 64; off <<= 1) {
            int v2 = __shfl_up(sc, off);
            if (lane >= off) sc += v2;
        }
        if (lane == 63) wsum[w] = sc;
        __syncthreads();

        int base = wred[0] + wred[1] + wred[2] + wred[3];
        int wb = 0;
        #pragma unroll
        for (int i = 0; i < 4; i++) wb += (i < w) ? wsum[i] : 0;
        if (n < N_NODES) node_off[n] = base + wb + (sc - c);   // exclusive, coalesced
        if (b == 0 && tid == 0) node_off[N_NODES] = N_EDGES;
        return;
    }

    int idx = b - P2_SCAN_BLOCKS;
    int pair = idx / P2_CHUNKS;
    int chunk = idx - pair * P2_CHUNKS;

    float* part = smem;                 // [4][64][13]
    float* Tlds = smem + 3328;          // [768]

    // stage T[pair][64][12] -> LDS (coalesced, 3 floats/thread)
    const float* Tp = T + pair * 768;
    #pragma unroll
    for (int i = tid; i < 768; i += 256) Tlds[i] = Tp[i];
    __syncthreads();

    int lane = tid & 63;                // bin within chunk
    int wq = tid >> 6;                  // k-quarter: waves 0..3 handle k = wq*16..+16
    int bin = chunk * 64 + lane;
    bool valid = (bin <= NBINS);
    int rb = valid ? bin : NBINS;       // clamp: stays in-bounds, store is guarded

    float acc[12];
    #pragma unroll
    for (int j = 0; j < 12; j++) acc[j] = 0.0f;
    #pragma unroll
    for (int kk = 0; kk < 16; kk++) {
        int k = wq * 16 + kk;
        float g = g_tT[(size_t)k * BINS1 + rb];   // 64 consecutive floats per wave
        const float* Tl = Tlds + k * 12;          // same addr across lanes -> broadcast
        #pragma unroll
        for (int j = 0; j < 12; j++) acc[j] += g * Tl[j];
    }

    float* pp = part + (size_t)wq * 64 * 13 + (size_t)lane * 13;  // stride 13: conflict-free
    #pragma unroll
    for (int j = 0; j < 12; j++) pp[j] = acc[j];
    __syncthreads();

    // final reduce + store: 768 outputs, 3 per thread, coalesced
    const float isc = 1.0f / 64.0f;
    float* svp = sv_table + (size_t)pair * BINS1 * 12 + (size_t)chunk * 64 * 12;
    #pragma unroll
    for (int i = 0; i < 3; i++) {
        int o = tid + 256 * i;          // o = bl*12 + j, bl in [0,64)
        int bl = o / 12;
        int j = o - bl * 12;
        if (chunk * 64 + bl <= NBINS) {
            float s = part[(size_t)0 * 832 + bl * 13 + j]
                    + part[(size_t)1 * 832 + bl * 13 + j]
                    + part[(size_t)2 * 832 + bl * 13 + j]
                    + part[(size_t)3 * 832 + bl * 13 + j];
            svp[o] = s * isc;
        }
    }
}

// ---------------- K3: csr build — eid scatter (4B/edge, replaces 64B ef rows) ---------
__global__ __launch_bounds__(256) void csr_kernel(
        const int* __restrict__ edst, const int* __restrict__ rank_e,
        const int* __restrict__ node_off, int* __restrict__ csr_eid) {
    int e = blockIdx.x * 256 + threadIdx.x;
    if (e >= N_EDGES) return;
    csr_eid[node_off[edst[e]] + rank_e[e]] = e;    // all loads coalesced; 4B scatter
}

// ---------------- K4: gather — full edge math inline, 8 threads/node, shfl reduce -----
// Same CSR slots / same stride-8 partials / same reduce as before -> identical
// summation order, no ef materialization.
__global__ __launch_bounds__(256) void gather_kernel(
        const float* __restrict__ pos, const int* __restrict__ batch,
        const int* __restrict__ esrc, const float* __restrict__ shifts,
        const float* __restrict__ cell, const int* __restrict__ A,
        const int* __restrict__ node_off, const int* __restrict__ csr_eid,
        const float* __restrict__ sv_table, float* __restrict__ out) {
    int t = blockIdx.x * 256 + threadIdx.x;     // (node, eighth)
    if (t >= N_NODES * 8) return;
    int n = t >> 3;
    int q = t & 7;
    int beg = node_off[n], end = node_off[n + 1];

    // destination-node data: identical for the node's 8 threads -> L1/L2 broadcast
    float pdx = pos[n * 3 + 0], pdy = pos[n * 3 + 1], pdz = pos[n * 3 + 2];
    int Ad = A[n];

    const float S3  = 1.7320508075688772f;
    const float S15 = 3.8729833462074170f;
    const float S5  = 2.2360679774997896f;

    float acc[36];
    #pragma unroll
    for (int j = 0; j < 36; j++) acc[j] = 0.0f;

    for (int p = beg + q; p < end; p += 8) {    // lanes q=0..7 cover consecutive slots
        int e = csr_eid[p];                     // 8 consecutive ints per node-group
        int s = esrc[e];
        int gb = batch[s];
        float t0 = shifts[e * 3 + 0], t1 = shifts[e * 3 + 1], t2 = shifts[e * 3 + 2];
        const float* C = cell + gb * 9;
        float shx = t0 * C[0] + t1 * C[3] + t2 * C[6];
        float shy = t0 * C[1] + t1 * C[4] + t2 * C[7];
        float shz = t0 * C[2] + t1 * C[5] + t2 * C[8];
        float ex = pdx - pos[s * 3 + 0] + shx;
        float ey = pdy - pos[s * 3 + 1] + shy;
        float ez = pdz - pos[s * 3 + 2] + shz;
        float r = sqrtf(ex * ex + ey * ey + ez * ez);
        float inv = 1.0f / fmaxf(r, 1e-9f);
        float x = ex * inv, y = ey * inv, z = ez * inv;

        float sv[12];
        if (r >= RMAX) {
            #pragma unroll
            for (int j = 0; j < 12; j++) sv[j] = 0.0f;
        } else {
            int pair = A[s] * 10 + Ad;
            float tt = r * ((float)NBINS / RMAX);
            int i = (int)tt;
            i = (i > NBINS - 1) ? (NBINS - 1) : i;
            float f = tt - (float)i;
            const float* r0 = sv_table + ((size_t)pair * BINS1 + i) * 12;  // 96B, L2
            #pragma unroll
            for (int j = 0; j < 12; j++) {
                float lo = r0[j], hi = r0[12 + j];
                sv[j] = lo + f * (hi - lo);
            }
        }

        float sh1v[3] = { S3 * y, S3 * z, S3 * x };
        float sh2v[5] = { S15 * x * y, S15 * y * z, 0.5f * S5 * (3.0f * z * z - 1.0f),
                          S15 * x * z, 0.5f * S15 * (x * x - y * y) };

        acc[0] += sv[0]; acc[1] += sv[1]; acc[2] += sv[2]; acc[3] += sv[3];
        #pragma unroll
        for (int w = 0; w < 4; w++) {
            float sw = sv[4 + w];
            #pragma unroll
            for (int j = 0; j < 3; j++) acc[4 + w * 3 + j] += sw * sh1v[j];
        }
        #pragma unroll
        for (int w = 0; w < 4; w++) {
            float sw = sv[8 + w];
            #pragma unroll
            for (int j = 0; j < 5; j++) acc[16 + w * 5 + j] += sw * sh2v[j];
        }
    }

    // reduce the 8 per-node threads (same wave: 8 | 64)
    #pragma unroll
    for (int j = 0; j < 36; j++) {
        acc[j] += __shfl_xor(acc[j], 1);
        acc[j] += __shfl_xor(acc[j], 2);
        acc[j] += __shfl_xor(acc[j], 4);
    }

    if (q == 0) {
        float c = 1.0f / fmaxf((float)(end - beg), 1.0f);
        float4* o4 = (float4*)out + (size_t)n * 9;
        #pragma unroll
        for (int k = 0; k < 9; k++)
            o4[k] = make_float4(acc[k * 4 + 0] * c, acc[k * 4 + 1] * c,
                                acc[k * 4 + 2] * c, acc[k * 4 + 3] * c);
    }
}

extern "C" void kernel_launch(void* const* d_in, const int* in_sizes, int n_in,
                              void* d_out, int out_size, void* d_ws, size_t ws_size,
                              hipStream_t stream) {
    const float* pos    = (const float*)d_in[0];
    const int*   A      = (const int*)d_in[1];
    const int*   batch  = (const int*)d_in[2];
    const int*   esrc   = (const int*)d_in[3];
    const int*   edst   = (const int*)d_in[4];
    const float* shifts = (const float*)d_in[5];
    const float* cell   = (const float*)d_in[6];
    const float* emb    = (const float*)d_in[7];
    const float* fw1    = (const float*)d_in[8];
    const float* fb1    = (const float*)d_in[9];
    const float* fw2    = (const float*)d_in[10];
    const float* fb2    = (const float*)d_in[11];
    const float* fw3    = (const float*)d_in[12];
    const float* fb3    = (const float*)d_in[13];
    const float* fcw1   = (const float*)d_in[14];
    const float* fcw2   = (const float*)d_in[15];
    const float* fcw3   = (const float*)d_in[16];
    const float* fcw4   = (const float*)d_in[17];
    float* out = (float*)d_out;

    char* ws = (char*)d_ws;
    float* T       = (float*)(ws + OFF_T);
    float* g_tT    = (float*)(ws + OFF_G);
    float* sv_table= (float*)(ws + OFF_SV);
    int*   node_off= (int*)(ws + OFF_NOFF);
    int*   cnt_i   = (int*)(ws + OFF_NCNT);
    int*   rank_e  = (int*)(ws + OFF_RANK);
    int*   csr_eid = (int*)(ws + OFF_CSR);

    hipMemsetAsync(cnt_i, 0, (size_t)N_NODES * 4, stream);

    prep1_kernel<<<P1_GRID, 256, 0, stream>>>(emb, fw1, fb1, fw2, fb2, fw3, fb3,
                                              fcw1, fcw2, fcw3, fcw4, edst,
                                              T, g_tT, cnt_i, rank_e);
    prep2_kernel<<<P2_GRID, 256, 0, stream>>>(cnt_i, node_off, T, g_tT, sv_table);
    csr_kernel<<<(N_EDGES + 255) / 256, 256, 0, stream>>>(edst, rank_e, node_off, csr_eid);
    gather_kernel<<<(N_NODES * 8 + 255) / 256, 256, 0, stream>>>(
        pos, batch, esrc, shifts, cell, A, node_off, csr_eid, sv_table, out);
}